// Round 6
// baseline (376.135 us; speedup 1.0000x reference)
//
#include <hip/hip_runtime.h>
#include <hip/hip_bf16.h>

#define NH 8
#define HD 32
#define NB 8
#define LQ 512
#define TK 8192

typedef __attribute__((ext_vector_type(8))) short short8;
typedef __attribute__((ext_vector_type(4))) float floatx4;

#define LOG2E 1.4426950408889634f
#define LN1EM6 13.815510557964274f   // -ln(1e-6)

__device__ inline float bf2f(ushort u) { return __uint_as_float(((unsigned)u) << 16); }
__device__ inline ushort f2bf(float f) {
    __hip_bfloat16 h = __float2bfloat16(f);
    return *reinterpret_cast<ushort*>(&h);
}
#define MFMA(a, b, c) __builtin_amdgcn_mfma_f32_16x16x32_bf16(a, b, c, 0, 0, 0)
#define EXP2F(x) __builtin_amdgcn_exp2f(x)   // v_exp_f32; avoids glibc __exp2f clash

// ---------------------------------------------------------------------------
// prep: emt3 = mask * log2(e), f32, fragment-linear [k>>6][q][quad*16+t*4+r]
// (k = 64c + 16t + 4quad + r) -> attn loads it straight into the MFMA
// C-operand (4 x b128 per (jt, 64-key iter)), zero VALU.  Plus bf16 weight
// conversion (fragment-linear).  NOTE: +1e-6 inside log FLOORS the mask at
// ln(1e-6): for |dt|>448 the mask is constant per side to 2e-5 -> attn skips
// loads there (but all keys still carry ~1e-3 softmax mass; NOT truncatable).
// ---------------------------------------------------------------------------
__global__ void prep_kernel(const float* __restrict__ rel_bias,
                            const float* __restrict__ mask_scale,
                            const float* __restrict__ in_w,
                            const float* __restrict__ out_w,
                            float* __restrict__ emt3, ushort* __restrict__ Wkv,
                            ushort* __restrict__ Wq, ushort* __restrict__ Wo) {
    int idx = blockIdx.x * blockDim.x + threadIdx.x;
    if (idx < LQ * TK) {
        int within = idx & 63;
        int qg = (idx >> 6) & 511;
        int c64 = idx >> 15;
        int quad = within >> 4, t = (within >> 2) & 3, r = within & 3;
        int k = c64 * 64 + t * 16 + quad * 4 + r;
        float tau = (float)qg * ((float)(TK - 1) / (float)(LQ - 1));
        float dt = (float)k - tau;
        float dtc = fminf(fmaxf(dt, -128.f), 128.f);
        int bi = (int)dtc + 128;              // trunc == astype(int32)
        float x = dt * (1.0f / 64.0f);
        float lg = __logf(__expf(-0.5f * x * x) + 1e-6f);
        emt3[idx] = mask_scale[0] * (rel_bias[bi] + lg) * LOG2E;
    } else {
        int i2 = idx - LQ * TK;
        const float* src;
        ushort* dst;
        int NT16, li;
        if (i2 < 131072) { li = i2; src = in_w + 65536; dst = Wkv; NT16 = 32; }
        else if (i2 < 196608) { li = i2 - 131072; src = in_w; dst = Wq; NT16 = 16; }
        else { li = i2 - 196608; src = out_w; dst = Wo; NT16 = 16; }
        int j = li & 7, lane = (li >> 3) & 63, rest = li >> 9;
        int jn = rest % NT16, ks = rest / NT16;
        int n = jn * 16 + (lane & 15), k = ks * 32 + (lane >> 4) * 8 + j;
        dst[li] = f2bf(src[n * 256 + k]);
    }
}

// ---------------------------------------------------------------------------
// bf16 MFMA projection, KV (blocks 0..1023) + Q (1024..1087) fused.
// Global stores line-contiguous: K/Q planes (h, 64 t, 32 d) are 4 KB
// contiguous, stored by wave w = h in 1KB-coalesced instrs; V^T stored as
// 128 B-contiguous t-segments. Q epilogue folds 1/sqrt(32)*log2(e).
// ---------------------------------------------------------------------------
__global__ __launch_bounds__(512, 2) void proj_kernel(
    const float* __restrict__ qin, const float* __restrict__ kv,
    const ushort* __restrict__ Wkv, const ushort* __restrict__ Wq,
    const float* __restrict__ in_b,
    ushort* __restrict__ Kb, ushort* __restrict__ Vtb, ushort* __restrict__ Qb) {
    __shared__ __align__(16) ushort smem[18432];

    int bid = blockIdx.x;
    int tid = threadIdx.x;
    int w = tid >> 6, lane = tid & 63;
    int q = lane & 15, quad = lane >> 4;
    bool isKV = bid < 1024;
    const float* X = isKV ? kv : qin;
    int m0 = isKV ? bid * 64 : (bid - 1024) * 64;

    // stage 64x256 X as bf16 A-fragments
    for (int i = tid; i < 4096; i += 512) {
        int m = i >> 6, j = i & 63;
        float4 x = *(const float4*)&X[(size_t)(m0 + m) * 256 + j * 4];
        int base = (((j >> 3) * 4 + (m >> 4)) * 64 + ((j >> 1) & 3) * 16 + (m & 15)) * 8 +
                   (j & 1) * 4;
        ushort4 h;
        h.x = f2bf(x.x); h.y = f2bf(x.y); h.z = f2bf(x.z); h.w = f2bf(x.w);
        *(ushort4*)&smem[base] = h;
    }
    __syncthreads();

    if (isKV) {
        floatx4 acc[4][4];
#pragma unroll
        for (int mt = 0; mt < 4; ++mt)
#pragma unroll
            for (int nt = 0; nt < 4; ++nt) acc[mt][nt] = (floatx4){0.f, 0.f, 0.f, 0.f};
        for (int ks = 0; ks < 8; ++ks) {
            short8 a[4];
#pragma unroll
            for (int mt = 0; mt < 4; ++mt)
                a[mt] = *(const short8*)&smem[((ks * 4 + mt) * 64 + lane) * 8];
#pragma unroll
            for (int nt = 0; nt < 4; ++nt) {
                short8 b = *(const short8*)&Wkv[((size_t)(ks * 32 + w * 4 + nt) * 64 + lane) * 8];
#pragma unroll
                for (int mt = 0; mt < 4; ++mt) acc[mt][nt] = MFMA(a[mt], b, acc[mt][nt]);
            }
        }
        float bn[4];
#pragma unroll
        for (int nt = 0; nt < 4; ++nt) bn[nt] = in_b[256 + w * 64 + nt * 16 + q];
        __syncthreads();
        int b_ = m0 >> 13, t0 = m0 & (TK - 1);
        // ---- phase 1: K (cols 0..255) via Ko[64][264]; wave w stores h=w ----
        if (w < 4) {
#pragma unroll
            for (int mt = 0; mt < 4; ++mt)
#pragma unroll
                for (int nt = 0; nt < 4; ++nt)
#pragma unroll
                    for (int r = 0; r < 4; ++r)
                        smem[(mt * 16 + quad * 4 + r) * 264 + w * 64 + nt * 16 + q] =
                            f2bf(acc[mt][nt][r] + bn[nt]);
        }
        __syncthreads();
        {
            uint4* dst = (uint4*)&Kb[((size_t)(b_ * 8 + w) * TK + t0) * 32];
#pragma unroll
            for (int j = 0; j < 4; ++j) {
                int f = j * 64 + lane;                   // uint4 index in 4KB plane
                int t = f >> 2, dpart = (f & 3) * 8;
                dst[f] = *(const uint4*)&smem[t * 264 + w * 32 + dpart];
            }
        }
        __syncthreads();
        // ---- phase 2: V^T (cols 256..511) via Vo[256][72]; 128B segments ----
        if (w >= 4) {
#pragma unroll
            for (int mt = 0; mt < 4; ++mt)
#pragma unroll
                for (int nt = 0; nt < 4; ++nt)
#pragma unroll
                    for (int r = 0; r < 4; ++r)
                        smem[((w - 4) * 64 + nt * 16 + q) * 72 + mt * 16 + quad * 4 + r] =
                            f2bf(acc[mt][nt][r] + bn[nt]);
        }
        __syncthreads();
#pragma unroll
        for (int j = 0; j < 4; ++j) {
            int f = j * 512 + tid;                       // 0..2047 uint4
            int row = f >> 3, seg = f & 7;               // row = v-col (h,d)
            *(uint4*)&Vtb[((size_t)((b_ * 8 + (row >> 5)) * 32 + (row & 31)) * TK) + t0 +
                          seg * 8] = *(const uint4*)&smem[row * 72 + seg * 8];
        }
    } else {
        floatx4 acc[4][2];
#pragma unroll
        for (int mt = 0; mt < 4; ++mt)
#pragma unroll
            for (int nt = 0; nt < 2; ++nt) acc[mt][nt] = (floatx4){0.f, 0.f, 0.f, 0.f};
        for (int ks = 0; ks < 8; ++ks) {
            short8 a[4];
#pragma unroll
            for (int mt = 0; mt < 4; ++mt)
                a[mt] = *(const short8*)&smem[((ks * 4 + mt) * 64 + lane) * 8];
#pragma unroll
            for (int nt = 0; nt < 2; ++nt) {
                short8 b = *(const short8*)&Wq[((size_t)(ks * 16 + w * 2 + nt) * 64 + lane) * 8];
#pragma unroll
                for (int mt = 0; mt < 4; ++mt) acc[mt][nt] = MFMA(a[mt], b, acc[mt][nt]);
            }
        }
        const float sc = 0.17677669529663687f * LOG2E;   // 1/sqrt(32)*log2(e)
        float bn[2];
#pragma unroll
        for (int nt = 0; nt < 2; ++nt) bn[nt] = in_b[w * 32 + nt * 16 + q];
        __syncthreads();
#pragma unroll
        for (int mt = 0; mt < 4; ++mt)
#pragma unroll
            for (int nt = 0; nt < 2; ++nt)
#pragma unroll
                for (int r = 0; r < 4; ++r)
                    smem[(mt * 16 + quad * 4 + r) * 264 + w * 32 + nt * 16 + q] =
                        f2bf((acc[mt][nt][r] + bn[nt]) * sc);
        __syncthreads();
        int b_ = m0 >> 9, r0 = m0 & (LQ - 1);
        uint4* dst = (uint4*)&Qb[((size_t)(b_ * 8 + w) * LQ + r0) * 32];
#pragma unroll
        for (int j = 0; j < 4; ++j) {
            int f = j * 64 + lane;
            int t = f >> 2, dpart = (f & 3) * 8;
            dst[f] = *(const uint4*)&smem[t * 264 + w * 32 + dpart];
        }
    }
}

// ---------------------------------------------------------------------------
// MFMA flash attention. Grid 512 x 512thr: block = (bh, 64q), 8 waves each
// own a contiguous 1024-key range (16 x 64-key iters). XCD pinning via
// bid&7 -> bh octet. Mask enters as the S-MFMA C-operand: in-band iters load
// f32 mask fragments (exact); |dt|>448 iters use a per-side constant
// (error 2e-5) -> no loads, no VALU. p = exp2(s) (log2e folded into Q+mask).
// bf16 pack via +0x8000 & v_perm. P^T via wave-private LDS (no loop barrier).
// 8 wave-partials (o, l) combined once at the end.
// ---------------------------------------------------------------------------
__global__ __launch_bounds__(512, 4) void attn_kernel(
    const ushort* __restrict__ Qb, const ushort* __restrict__ Kb,
    const ushort* __restrict__ Vtb, const float* __restrict__ emt3,
    const float* __restrict__ rel_bias, const float* __restrict__ mscale,
    ushort* __restrict__ attnb) {
    __shared__ __align__(16) char sm[71680];
    ushort(*Pb)[16][72] = (ushort(*)[16][72])sm;   // [8][16][72] = 18432 B
    float* obuf = (float*)sm;                       // [8][4][32][17] = 69632 B
    float* lbuf = (float*)(sm + 69632);             // [8][4][16]    =  2048 B

    int bid = blockIdx.x;
    int bh = (bid & 7) * 8 + ((bid >> 3) & 7);
    int qb = bid >> 6;
    int tid = threadIdx.x;
    int w = tid >> 6, lane = tid & 63;
    int q = lane & 15, quad = lane >> 4;
    int q0 = qb * 64;

    float ms = mscale[0];
    float lmlo = ms * (rel_bias[0] - LN1EM6) * LOG2E;
    float lmhi = ms * (rel_bias[256] - LN1EM6) * LOG2E;

    const float S = (float)(TK - 1) / (float)(LQ - 1);
    float blo[4], bhi[4];
#pragma unroll
    for (int jt = 0; jt < 4; ++jt) {
        blo[jt] = (float)(q0 + jt * 16) * S - 448.0f;
        bhi[jt] = (float)(q0 + jt * 16 + 15) * S + 448.0f;
    }

    short8 qfrag[4];
#pragma unroll
    for (int jt = 0; jt < 4; ++jt)
        qfrag[jt] = *(const short8*)&Qb[((size_t)bh * LQ + q0 + jt * 16 + q) * HD + quad * 8];

    const ushort* kp = Kb + (size_t)bh * TK * HD + ((size_t)(w * 1024) + q) * 32 + quad * 8;
    const ushort* vp0 = Vtb + (size_t)bh * HD * TK + (size_t)q * TK + w * 1024 + quad * 8;
    const ushort* vp1 = vp0 + (size_t)16 * TK;
    const float* ep = emt3 + ((size_t)(w * 16) * 512 + q0 + q) * 64 + quad * 16;

    floatx4 o0[4], o1[4];
#pragma unroll
    for (int jt = 0; jt < 4; ++jt) {
        o0[jt] = (floatx4){0.f, 0.f, 0.f, 0.f};
        o1[jt] = (floatx4){0.f, 0.f, 0.f, 0.f};
    }
    float lsum[4] = {0.f, 0.f, 0.f, 0.f};

    int k0 = w * 1024;
    for (int i = 0; i < 16; ++i) {
        float k0f = (float)k0;

        short8 kf[4];
#pragma unroll
        for (int t = 0; t < 4; ++t) kf[t] = *(const short8*)(kp + t * 512);
        short8 vf[2][2];
#pragma unroll
        for (int t2 = 0; t2 < 2; ++t2) {
            vf[t2][0] = *(const short8*)(vp0 + t2 * 32);
            vf[t2][1] = *(const short8*)(vp1 + t2 * 32);
        }

#pragma unroll
        for (int jt = 0; jt < 4; ++jt) {
            floatx4 s[4];
            bool below = (k0f + 63.0f) < blo[jt];
            bool above = k0f > bhi[jt];
            if (below || above) {
                float lm = below ? lmlo : lmhi;
                floatx4 c = {lm, lm, lm, lm};
#pragma unroll
                for (int t = 0; t < 4; ++t) s[t] = MFMA(kf[t], qfrag[jt], c);
            } else {
                const float* e = ep + jt * 1024;
#pragma unroll
                for (int t = 0; t < 4; ++t)
                    s[t] = MFMA(kf[t], qfrag[jt], *(const floatx4*)(e + t * 4));
            }

#pragma unroll
            for (int t = 0; t < 4; ++t) {
                float p0 = EXP2F(s[t][0]);
                float p1 = EXP2F(s[t][1]);
                float p2 = EXP2F(s[t][2]);
                float p3 = EXP2F(s[t][3]);
                lsum[jt] += (p0 + p1) + (p2 + p3);
                uint a0 = __float_as_uint(p0) + 0x8000u;
                uint a1 = __float_as_uint(p1) + 0x8000u;
                uint a2 = __float_as_uint(p2) + 0x8000u;
                uint a3 = __float_as_uint(p3) + 0x8000u;
                uint2 pk;
                pk.x = __builtin_amdgcn_perm(a1, a0, 0x07060302u);
                pk.y = __builtin_amdgcn_perm(a3, a2, 0x07060302u);
                *(uint2*)&Pb[w][q][t * 16 + quad * 4] = pk;
            }
#pragma unroll
            for (int t2 = 0; t2 < 2; ++t2) {
                short8 pf = *(const short8*)&Pb[w][q][t2 * 32 + quad * 8];
                o0[jt] = MFMA(vf[t2][0], pf, o0[jt]);
                o1[jt] = MFMA(vf[t2][1], pf, o1[jt]);
            }
        }
        k0 += 64;
        kp += 64 * 32;
        vp0 += 64;
        vp1 += 64;
        ep += (size_t)512 * 64;
    }

    __syncthreads();   // all waves done with Pb before obuf overwrites it
#pragma unroll
    for (int jt = 0; jt < 4; ++jt) {
        float ls = lsum[jt];
        ls += __shfl_xor(ls, 16);
        ls += __shfl_xor(ls, 32);
#pragma unroll
        for (int r = 0; r < 4; ++r) {
            obuf[((w * 4 + jt) * 32 + quad * 4 + r) * 17 + q] = o0[jt][r];
            obuf[((w * 4 + jt) * 32 + 16 + quad * 4 + r) * 17 + q] = o1[jt][r];
        }
        if (quad == 0) lbuf[(w * 4 + jt) * 16 + q] = ls;
    }
    __syncthreads();

    int b_ = bh >> 3, h = bh & 7;
    for (int e = tid; e < 2048; e += 512) {
        int qq = e >> 5, d = e & 31;
        int jt = qq >> 4, ql = qq & 15;
        float ov = 0.f, L = 0.f;
#pragma unroll
        for (int ww = 0; ww < 8; ++ww) {
            ov += obuf[((ww * 4 + jt) * 32 + d) * 17 + ql];
            L += lbuf[(ww * 4 + jt) * 16 + ql];
        }
        attnb[((size_t)(b_ * LQ + q0 + qq)) * 256 + h * 32 + d] = f2bf(ov / L);
    }
}

// ---------------------------------------------------------------------------
// Output projection: attnb (bf16) @ Wo^T + out_b -> f32.
// ---------------------------------------------------------------------------
__global__ __launch_bounds__(512) void oproj_kernel(
    const ushort* __restrict__ attnb, const ushort* __restrict__ Wo,
    const float* __restrict__ out_b, float* __restrict__ out) {
    int bid = blockIdx.x;
    int tid = threadIdx.x;
    int w = tid >> 6, lane = tid & 63;
    int q = lane & 15, quad = lane >> 4;
    int m0 = bid * 32;

    floatx4 acc[2][2];
#pragma unroll
    for (int mt = 0; mt < 2; ++mt)
#pragma unroll
        for (int nt = 0; nt < 2; ++nt) acc[mt][nt] = (floatx4){0.f, 0.f, 0.f, 0.f};

    for (int ks = 0; ks < 8; ++ks) {
        short8 a[2];
#pragma unroll
        for (int mt = 0; mt < 2; ++mt)
            a[mt] = *(const short8*)&attnb[(size_t)(m0 + mt * 16 + q) * 256 + ks * 32 + quad * 8];
#pragma unroll
        for (int nt = 0; nt < 2; ++nt) {
            short8 b = *(const short8*)&Wo[((size_t)(ks * 16 + w * 2 + nt) * 64 + lane) * 8];
#pragma unroll
            for (int mt = 0; mt < 2; ++mt) acc[mt][nt] = MFMA(a[mt], b, acc[mt][nt]);
        }
    }
#pragma unroll
    for (int mt = 0; mt < 2; ++mt)
#pragma unroll
        for (int nt = 0; nt < 2; ++nt) {
            float bn = out_b[w * 32 + nt * 16 + q];
#pragma unroll
            for (int r = 0; r < 4; ++r)
                out[(size_t)(m0 + mt * 16 + quad * 4 + r) * 256 + w * 32 + nt * 16 + q] =
                    acc[mt][nt][r] + bn;
        }
}

// ---------------------------------------------------------------------------
// Launch
// ---------------------------------------------------------------------------
extern "C" void kernel_launch(void* const* d_in, const int* in_sizes, int n_in,
                              void* d_out, int out_size, void* d_ws,
                              size_t ws_size, hipStream_t stream) {
    const float* q        = (const float*)d_in[0];
    const float* kv       = (const float*)d_in[1];
    const float* in_w     = (const float*)d_in[2];
    const float* in_b     = (const float*)d_in[3];
    const float* out_w    = (const float*)d_in[4];
    const float* out_b    = (const float*)d_in[5];
    const float* rel_bias = (const float*)d_in[6];
    const float* mscale   = (const float*)d_in[7];

    ushort* p = (ushort*)d_ws;
    ushort* Kb    = p; p += (size_t)64 * TK * HD;    // 33.5 MB
    ushort* Vtb   = p; p += (size_t)64 * TK * HD;    // 33.5 MB
    ushort* Qb    = p; p += (size_t)64 * LQ * HD;    // 2.1 MB
    ushort* attnb = p; p += (size_t)NB * LQ * 256;   // 2.1 MB
    ushort* Wkv   = p; p += 131072;
    ushort* Wq    = p; p += 65536;
    ushort* Wo    = p; p += 65536;
    float* emt3   = (float*)p;                       // 16.8 MB (f32)

    prep_kernel<<<17408, 256, 0, stream>>>(rel_bias, mscale, in_w, out_w,
                                           emt3, Wkv, Wq, Wo);

    proj_kernel<<<1088, 512, 0, stream>>>(q, kv, Wkv, Wq, in_b, Kb, Vtb, Qb);

    attn_kernel<<<512, 512, 0, stream>>>(Qb, Kb, Vtb, emt3, rel_bias, mscale, attnb);

    oproj_kernel<<<128, 512, 0, stream>>>(attnb, Wo, out_b, (float*)d_out);
}

// Round 7
// 264.019 us; speedup vs baseline: 1.4247x; 1.4247x over previous
//
#include <hip/hip_runtime.h>
#include <hip/hip_bf16.h>

#define NH 8
#define HD 32
#define NB 8
#define LQ 512
#define TK 8192

typedef __attribute__((ext_vector_type(8))) short short8;
typedef __attribute__((ext_vector_type(4))) float floatx4;

#define LOG2E 1.4426950408889634f
#define LN1EM6 13.815510557964274f   // -ln(1e-6)

__device__ inline float bf2f(ushort u) { return __uint_as_float(((unsigned)u) << 16); }
__device__ inline ushort f2bf(float f) {
    __hip_bfloat16 h = __float2bfloat16(f);
    return *reinterpret_cast<ushort*>(&h);
}
#define MFMA(a, b, c) __builtin_amdgcn_mfma_f32_16x16x32_bf16(a, b, c, 0, 0, 0)
#define EXP2F(x) __builtin_amdgcn_exp2f(x)   // v_exp_f32; avoids glibc __exp2f clash

// ---------------------------------------------------------------------------
// prep: emt3 = mask * log2(e), f32, fragment-linear [k>>6][q][quad*16+t*4+r]
// (k = 64c + 16t + 4quad + r) -> attn loads it straight into the MFMA
// C-operand (4 x b128 per (jt, 64-key iter)), zero VALU.  Plus bf16 weight
// conversion (fragment-linear).  NOTE: +1e-6 inside log FLOORS the mask at
// ln(1e-6): for |dt|>448 the mask is constant per side to 2e-5 -> attn skips
// loads there (but all keys still carry ~1e-3 softmax mass; NOT truncatable).
// ---------------------------------------------------------------------------
__global__ void prep_kernel(const float* __restrict__ rel_bias,
                            const float* __restrict__ mask_scale,
                            const float* __restrict__ in_w,
                            const float* __restrict__ out_w,
                            float* __restrict__ emt3, ushort* __restrict__ Wkv,
                            ushort* __restrict__ Wq, ushort* __restrict__ Wo) {
    int idx = blockIdx.x * blockDim.x + threadIdx.x;
    if (idx < LQ * TK) {
        int within = idx & 63;
        int qg = (idx >> 6) & 511;
        int c64 = idx >> 15;
        int quad = within >> 4, t = (within >> 2) & 3, r = within & 3;
        int k = c64 * 64 + t * 16 + quad * 4 + r;
        float tau = (float)qg * ((float)(TK - 1) / (float)(LQ - 1));
        float dt = (float)k - tau;
        float dtc = fminf(fmaxf(dt, -128.f), 128.f);
        int bi = (int)dtc + 128;              // trunc == astype(int32)
        float x = dt * (1.0f / 64.0f);
        float lg = __logf(__expf(-0.5f * x * x) + 1e-6f);
        emt3[idx] = mask_scale[0] * (rel_bias[bi] + lg) * LOG2E;
    } else {
        int i2 = idx - LQ * TK;
        const float* src;
        ushort* dst;
        int NT16, li;
        if (i2 < 131072) { li = i2; src = in_w + 65536; dst = Wkv; NT16 = 32; }
        else if (i2 < 196608) { li = i2 - 131072; src = in_w; dst = Wq; NT16 = 16; }
        else { li = i2 - 196608; src = out_w; dst = Wo; NT16 = 16; }
        int j = li & 7, lane = (li >> 3) & 63, rest = li >> 9;
        int jn = rest % NT16, ks = rest / NT16;
        int n = jn * 16 + (lane & 15), k = ks * 32 + (lane >> 4) * 8 + j;
        dst[li] = f2bf(src[n * 256 + k]);
    }
}

// ---------------------------------------------------------------------------
// bf16 MFMA projection, KV (blocks 0..1023) + Q (1024..1087) fused.
// Global stores line-contiguous: K/Q planes (h, 64 t, 32 d) are 4 KB
// contiguous, stored by wave w = h in 1KB-coalesced instrs; V^T stored as
// 128 B-contiguous t-segments. Q epilogue folds 1/sqrt(32)*log2(e).
// ---------------------------------------------------------------------------
__global__ __launch_bounds__(512, 2) void proj_kernel(
    const float* __restrict__ qin, const float* __restrict__ kv,
    const ushort* __restrict__ Wkv, const ushort* __restrict__ Wq,
    const float* __restrict__ in_b,
    ushort* __restrict__ Kb, ushort* __restrict__ Vtb, ushort* __restrict__ Qb) {
    __shared__ __align__(16) ushort smem[18432];

    int bid = blockIdx.x;
    int tid = threadIdx.x;
    int w = tid >> 6, lane = tid & 63;
    int q = lane & 15, quad = lane >> 4;
    bool isKV = bid < 1024;
    const float* X = isKV ? kv : qin;
    int m0 = isKV ? bid * 64 : (bid - 1024) * 64;

    // stage 64x256 X as bf16 A-fragments
    for (int i = tid; i < 4096; i += 512) {
        int m = i >> 6, j = i & 63;
        float4 x = *(const float4*)&X[(size_t)(m0 + m) * 256 + j * 4];
        int base = (((j >> 3) * 4 + (m >> 4)) * 64 + ((j >> 1) & 3) * 16 + (m & 15)) * 8 +
                   (j & 1) * 4;
        ushort4 h;
        h.x = f2bf(x.x); h.y = f2bf(x.y); h.z = f2bf(x.z); h.w = f2bf(x.w);
        *(ushort4*)&smem[base] = h;
    }
    __syncthreads();

    if (isKV) {
        floatx4 acc[4][4];
#pragma unroll
        for (int mt = 0; mt < 4; ++mt)
#pragma unroll
            for (int nt = 0; nt < 4; ++nt) acc[mt][nt] = (floatx4){0.f, 0.f, 0.f, 0.f};
        for (int ks = 0; ks < 8; ++ks) {
            short8 a[4];
#pragma unroll
            for (int mt = 0; mt < 4; ++mt)
                a[mt] = *(const short8*)&smem[((ks * 4 + mt) * 64 + lane) * 8];
#pragma unroll
            for (int nt = 0; nt < 4; ++nt) {
                short8 b = *(const short8*)&Wkv[((size_t)(ks * 32 + w * 4 + nt) * 64 + lane) * 8];
#pragma unroll
                for (int mt = 0; mt < 4; ++mt) acc[mt][nt] = MFMA(a[mt], b, acc[mt][nt]);
            }
        }
        float bn[4];
#pragma unroll
        for (int nt = 0; nt < 4; ++nt) bn[nt] = in_b[256 + w * 64 + nt * 16 + q];
        __syncthreads();
        int b_ = m0 >> 13, t0 = m0 & (TK - 1);
        // ---- phase 1: K (cols 0..255) via Ko[64][264]; wave w stores h=w ----
        if (w < 4) {
#pragma unroll
            for (int mt = 0; mt < 4; ++mt)
#pragma unroll
                for (int nt = 0; nt < 4; ++nt)
#pragma unroll
                    for (int r = 0; r < 4; ++r)
                        smem[(mt * 16 + quad * 4 + r) * 264 + w * 64 + nt * 16 + q] =
                            f2bf(acc[mt][nt][r] + bn[nt]);
        }
        __syncthreads();
        {
            uint4* dst = (uint4*)&Kb[((size_t)(b_ * 8 + w) * TK + t0) * 32];
#pragma unroll
            for (int j = 0; j < 4; ++j) {
                int f = j * 64 + lane;                   // uint4 index in 4KB plane
                int t = f >> 2, dpart = (f & 3) * 8;
                dst[f] = *(const uint4*)&smem[t * 264 + w * 32 + dpart];
            }
        }
        __syncthreads();
        // ---- phase 2: V^T (cols 256..511) via Vo[256][72]; 128B segments ----
        if (w >= 4) {
#pragma unroll
            for (int mt = 0; mt < 4; ++mt)
#pragma unroll
                for (int nt = 0; nt < 4; ++nt)
#pragma unroll
                    for (int r = 0; r < 4; ++r)
                        smem[((w - 4) * 64 + nt * 16 + q) * 72 + mt * 16 + quad * 4 + r] =
                            f2bf(acc[mt][nt][r] + bn[nt]);
        }
        __syncthreads();
#pragma unroll
        for (int j = 0; j < 4; ++j) {
            int f = j * 512 + tid;                       // 0..2047 uint4
            int row = f >> 3, seg = f & 7;               // row = v-col (h,d)
            *(uint4*)&Vtb[((size_t)((b_ * 8 + (row >> 5)) * 32 + (row & 31)) * TK) + t0 +
                          seg * 8] = *(const uint4*)&smem[row * 72 + seg * 8];
        }
    } else {
        floatx4 acc[4][2];
#pragma unroll
        for (int mt = 0; mt < 4; ++mt)
#pragma unroll
            for (int nt = 0; nt < 2; ++nt) acc[mt][nt] = (floatx4){0.f, 0.f, 0.f, 0.f};
        for (int ks = 0; ks < 8; ++ks) {
            short8 a[4];
#pragma unroll
            for (int mt = 0; mt < 4; ++mt)
                a[mt] = *(const short8*)&smem[((ks * 4 + mt) * 64 + lane) * 8];
#pragma unroll
            for (int nt = 0; nt < 2; ++nt) {
                short8 b = *(const short8*)&Wq[((size_t)(ks * 16 + w * 2 + nt) * 64 + lane) * 8];
#pragma unroll
                for (int mt = 0; mt < 4; ++mt) acc[mt][nt] = MFMA(a[mt], b, acc[mt][nt]);
            }
        }
        const float sc = 0.17677669529663687f * LOG2E;   // 1/sqrt(32)*log2(e)
        float bn[2];
#pragma unroll
        for (int nt = 0; nt < 2; ++nt) bn[nt] = in_b[w * 32 + nt * 16 + q];
        __syncthreads();
#pragma unroll
        for (int mt = 0; mt < 4; ++mt)
#pragma unroll
            for (int nt = 0; nt < 2; ++nt)
#pragma unroll
                for (int r = 0; r < 4; ++r)
                    smem[(mt * 16 + quad * 4 + r) * 264 + w * 32 + nt * 16 + q] =
                        f2bf((acc[mt][nt][r] + bn[nt]) * sc);
        __syncthreads();
        int b_ = m0 >> 9, r0 = m0 & (LQ - 1);
        uint4* dst = (uint4*)&Qb[((size_t)(b_ * 8 + w) * LQ + r0) * 32];
#pragma unroll
        for (int j = 0; j < 4; ++j) {
            int f = j * 64 + lane;
            int t = f >> 2, dpart = (f & 3) * 8;
            dst[f] = *(const uint4*)&smem[t * 264 + w * 32 + dpart];
        }
    }
}

// ---------------------------------------------------------------------------
// MFMA flash attention. Grid 512 x 512thr: block = (bh, 64q), 8 waves each
// own a contiguous 1024-key range (16 x 64-key iters). XCD pinning via
// bid&7 -> bh octet. Mask enters as the S-MFMA C-operand: in-band iters load
// f32 mask fragments (exact); |dt|>448 iters use a per-side constant
// (error 2e-5) -> no loads, no VALU. p = exp2(s) (log2e folded into Q+mask).
// bf16 pack via +0x8000 & v_perm. P^T via wave-private LDS (no loop barrier).
// 8 wave-partials (o, l) combined once at the end.
// NOTE round-7: NO min-waves clause. (512,4) capped VGPR at 64 -> the 32-float
// o-accumulators spilled to scratch every iter (466 MB HBM writes, 220 µs).
// Natural allocation ~120-160 VGPR still gives 12-16 waves/CU.
// ---------------------------------------------------------------------------
__global__ __launch_bounds__(512) void attn_kernel(
    const ushort* __restrict__ Qb, const ushort* __restrict__ Kb,
    const ushort* __restrict__ Vtb, const float* __restrict__ emt3,
    const float* __restrict__ rel_bias, const float* __restrict__ mscale,
    ushort* __restrict__ attnb) {
    __shared__ __align__(16) char sm[71680];
    ushort(*Pb)[16][72] = (ushort(*)[16][72])sm;   // [8][16][72] = 18432 B
    float* obuf = (float*)sm;                       // [8][4][32][17] = 69632 B
    float* lbuf = (float*)(sm + 69632);             // [8][4][16]    =  2048 B

    int bid = blockIdx.x;
    int bh = (bid & 7) * 8 + ((bid >> 3) & 7);
    int qb = bid >> 6;
    int tid = threadIdx.x;
    int w = tid >> 6, lane = tid & 63;
    int q = lane & 15, quad = lane >> 4;
    int q0 = qb * 64;

    float ms = mscale[0];
    float lmlo = ms * (rel_bias[0] - LN1EM6) * LOG2E;
    float lmhi = ms * (rel_bias[256] - LN1EM6) * LOG2E;

    const float S = (float)(TK - 1) / (float)(LQ - 1);
    float blo[4], bhi[4];
#pragma unroll
    for (int jt = 0; jt < 4; ++jt) {
        blo[jt] = (float)(q0 + jt * 16) * S - 448.0f;
        bhi[jt] = (float)(q0 + jt * 16 + 15) * S + 448.0f;
    }

    short8 qfrag[4];
#pragma unroll
    for (int jt = 0; jt < 4; ++jt)
        qfrag[jt] = *(const short8*)&Qb[((size_t)bh * LQ + q0 + jt * 16 + q) * HD + quad * 8];

    const ushort* kp = Kb + (size_t)bh * TK * HD + ((size_t)(w * 1024) + q) * 32 + quad * 8;
    const ushort* vp0 = Vtb + (size_t)bh * HD * TK + (size_t)q * TK + w * 1024 + quad * 8;
    const ushort* vp1 = vp0 + (size_t)16 * TK;
    const float* ep = emt3 + ((size_t)(w * 16) * 512 + q0 + q) * 64 + quad * 16;

    floatx4 o0[4], o1[4];
#pragma unroll
    for (int jt = 0; jt < 4; ++jt) {
        o0[jt] = (floatx4){0.f, 0.f, 0.f, 0.f};
        o1[jt] = (floatx4){0.f, 0.f, 0.f, 0.f};
    }
    float lsum[4] = {0.f, 0.f, 0.f, 0.f};

    int k0 = w * 1024;
    for (int i = 0; i < 16; ++i) {
        float k0f = (float)k0;

        short8 kf[4];
#pragma unroll
        for (int t = 0; t < 4; ++t) kf[t] = *(const short8*)(kp + t * 512);
        short8 vf[2][2];
#pragma unroll
        for (int t2 = 0; t2 < 2; ++t2) {
            vf[t2][0] = *(const short8*)(vp0 + t2 * 32);
            vf[t2][1] = *(const short8*)(vp1 + t2 * 32);
        }

#pragma unroll
        for (int jt = 0; jt < 4; ++jt) {
            floatx4 s[4];
            bool below = (k0f + 63.0f) < blo[jt];
            bool above = k0f > bhi[jt];
            if (below || above) {
                float lm = below ? lmlo : lmhi;
                floatx4 c = {lm, lm, lm, lm};
#pragma unroll
                for (int t = 0; t < 4; ++t) s[t] = MFMA(kf[t], qfrag[jt], c);
            } else {
                const float* e = ep + jt * 1024;
#pragma unroll
                for (int t = 0; t < 4; ++t)
                    s[t] = MFMA(kf[t], qfrag[jt], *(const floatx4*)(e + t * 4));
            }

#pragma unroll
            for (int t = 0; t < 4; ++t) {
                float p0 = EXP2F(s[t][0]);
                float p1 = EXP2F(s[t][1]);
                float p2 = EXP2F(s[t][2]);
                float p3 = EXP2F(s[t][3]);
                lsum[jt] += (p0 + p1) + (p2 + p3);
                uint a0 = __float_as_uint(p0) + 0x8000u;
                uint a1 = __float_as_uint(p1) + 0x8000u;
                uint a2 = __float_as_uint(p2) + 0x8000u;
                uint a3 = __float_as_uint(p3) + 0x8000u;
                uint2 pk;
                pk.x = __builtin_amdgcn_perm(a1, a0, 0x07060302u);
                pk.y = __builtin_amdgcn_perm(a3, a2, 0x07060302u);
                *(uint2*)&Pb[w][q][t * 16 + quad * 4] = pk;
            }
#pragma unroll
            for (int t2 = 0; t2 < 2; ++t2) {
                short8 pf = *(const short8*)&Pb[w][q][t2 * 32 + quad * 8];
                o0[jt] = MFMA(vf[t2][0], pf, o0[jt]);
                o1[jt] = MFMA(vf[t2][1], pf, o1[jt]);
            }
        }
        k0 += 64;
        kp += 64 * 32;
        vp0 += 64;
        vp1 += 64;
        ep += (size_t)512 * 64;
    }

    __syncthreads();   // all waves done with Pb before obuf overwrites it
#pragma unroll
    for (int jt = 0; jt < 4; ++jt) {
        float ls = lsum[jt];
        ls += __shfl_xor(ls, 16);
        ls += __shfl_xor(ls, 32);
#pragma unroll
        for (int r = 0; r < 4; ++r) {
            obuf[((w * 4 + jt) * 32 + quad * 4 + r) * 17 + q] = o0[jt][r];
            obuf[((w * 4 + jt) * 32 + 16 + quad * 4 + r) * 17 + q] = o1[jt][r];
        }
        if (quad == 0) lbuf[(w * 4 + jt) * 16 + q] = ls;
    }
    __syncthreads();

    int b_ = bh >> 3, h = bh & 7;
    for (int e = tid; e < 2048; e += 512) {
        int qq = e >> 5, d = e & 31;
        int jt = qq >> 4, ql = qq & 15;
        float ov = 0.f, L = 0.f;
#pragma unroll
        for (int ww = 0; ww < 8; ++ww) {
            ov += obuf[((ww * 4 + jt) * 32 + d) * 17 + ql];
            L += lbuf[(ww * 4 + jt) * 16 + ql];
        }
        attnb[((size_t)(b_ * LQ + q0 + qq)) * 256 + h * 32 + d] = f2bf(ov / L);
    }
}

// ---------------------------------------------------------------------------
// Output projection: attnb (bf16) @ Wo^T + out_b -> f32.
// ---------------------------------------------------------------------------
__global__ __launch_bounds__(512) void oproj_kernel(
    const ushort* __restrict__ attnb, const ushort* __restrict__ Wo,
    const float* __restrict__ out_b, float* __restrict__ out) {
    int bid = blockIdx.x;
    int tid = threadIdx.x;
    int w = tid >> 6, lane = tid & 63;
    int q = lane & 15, quad = lane >> 4;
    int m0 = bid * 32;

    floatx4 acc[2][2];
#pragma unroll
    for (int mt = 0; mt < 2; ++mt)
#pragma unroll
        for (int nt = 0; nt < 2; ++nt) acc[mt][nt] = (floatx4){0.f, 0.f, 0.f, 0.f};

    for (int ks = 0; ks < 8; ++ks) {
        short8 a[2];
#pragma unroll
        for (int mt = 0; mt < 2; ++mt)
            a[mt] = *(const short8*)&attnb[(size_t)(m0 + mt * 16 + q) * 256 + ks * 32 + quad * 8];
#pragma unroll
        for (int nt = 0; nt < 2; ++nt) {
            short8 b = *(const short8*)&Wo[((size_t)(ks * 16 + w * 2 + nt) * 64 + lane) * 8];
#pragma unroll
            for (int mt = 0; mt < 2; ++mt) acc[mt][nt] = MFMA(a[mt], b, acc[mt][nt]);
        }
    }
#pragma unroll
    for (int mt = 0; mt < 2; ++mt)
#pragma unroll
        for (int nt = 0; nt < 2; ++nt) {
            float bn = out_b[w * 32 + nt * 16 + q];
#pragma unroll
            for (int r = 0; r < 4; ++r)
                out[(size_t)(m0 + mt * 16 + quad * 4 + r) * 256 + w * 32 + nt * 16 + q] =
                    acc[mt][nt][r] + bn;
        }
}

// ---------------------------------------------------------------------------
// Launch
// ---------------------------------------------------------------------------
extern "C" void kernel_launch(void* const* d_in, const int* in_sizes, int n_in,
                              void* d_out, int out_size, void* d_ws,
                              size_t ws_size, hipStream_t stream) {
    const float* q        = (const float*)d_in[0];
    const float* kv       = (const float*)d_in[1];
    const float* in_w     = (const float*)d_in[2];
    const float* in_b     = (const float*)d_in[3];
    const float* out_w    = (const float*)d_in[4];
    const float* out_b    = (const float*)d_in[5];
    const float* rel_bias = (const float*)d_in[6];
    const float* mscale   = (const float*)d_in[7];

    ushort* p = (ushort*)d_ws;
    ushort* Kb    = p; p += (size_t)64 * TK * HD;    // 33.5 MB
    ushort* Vtb   = p; p += (size_t)64 * TK * HD;    // 33.5 MB
    ushort* Qb    = p; p += (size_t)64 * LQ * HD;    // 2.1 MB
    ushort* attnb = p; p += (size_t)NB * LQ * 256;   // 2.1 MB
    ushort* Wkv   = p; p += 131072;
    ushort* Wq    = p; p += 65536;
    ushort* Wo    = p; p += 65536;
    float* emt3   = (float*)p;                       // 16.8 MB (f32)

    prep_kernel<<<17408, 256, 0, stream>>>(rel_bias, mscale, in_w, out_w,
                                           emt3, Wkv, Wq, Wo);

    proj_kernel<<<1088, 512, 0, stream>>>(q, kv, Wkv, Wq, in_b, Kb, Vtb, Qb);

    attn_kernel<<<512, 512, 0, stream>>>(Qb, Kb, Vtb, emt3, rel_bias, mscale, attnb);

    oproj_kernel<<<128, 512, 0, stream>>>(attnb, Wo, out_b, (float*)d_out);
}